// Round 1
// baseline (353.649 us; speedup 1.0000x reference)
//
#include <hip/hip_runtime.h>

// RelationLayer fused implementation (all fp32 — threshold is 8*eps_fp32*scale,
// so no bf16 MFMA; CDNA4 has no fp32 MFMA -> VALU GEMMs).
//
// Pipeline (5 stream ops):
//  memset  : zero win3 conv region (atomic tap accumulation)
//  conv    : y_T[c][row] (row=l*32+b), win1 stores / win3 3-tap atomicAdd. Bias
//            skipped: BN subtracts the mean, conv bias cancels exactly.
//  stats   : per-channel mean/var over 2048 samples -> scale/shift (folds BN+gamma/beta)
//  ab      : h = leaky(y*scale+shift)*mask on the fly; a = h@w0[:C], bb = h@w0[C:]
//  pair    : per (i, b-pair) block: p0=leaky(a_i+bb_j+b0) as 128x128 LDS tile,
//            3 fused 128x128 layers (8x8 reg tiles), j-mean reduction, output MLP,
//            final mask — writes d_out directly. Never materializes (L,L,B,128).

#define LL 64
#define BB 32
#define DIN 512
#define CCH 384
#define DM 128
#define DOUT 512
#define RS 132  // LDS row stride (128 + 4 pad), keeps 16B alignment (528%16==0)

__device__ __forceinline__ float leaky(float x) { return x >= 0.f ? x : 0.1f * x; }

// ---------------------------------------------------------------- conv ------
// grid 320 = 64 row-tiles x 5 variants (2x win1 col-halves, 3x win3 taps)
__global__ __launch_bounds__(256) void conv_kernel(
    const float* __restrict__ x, const float* __restrict__ mask,
    const float* __restrict__ cw0, const float* __restrict__ cw1,
    float* __restrict__ yT)
{
  __shared__ float As[32 * 36];    // [k][r], stride 36 (144B rows, 16B aligned)
  __shared__ float Ws[32 * 132];   // [k][c], stride 132
  int bx = blockIdx.x;
  int rt = bx & 63;
  int var = bx >> 6;
  int row0 = rt * 32;
  int tid = threadIdx.x;

  int dt = 0, wstride = 512, cbase = 0;
  const float* wsrc = cw0;
  bool at = false;
  if (var < 2) { cbase = var * 128; wsrc = cw0 + cbase * 512; }
  else { int t = var - 2; dt = t - 1; wsrc = cw1 + t * 512; wstride = 1536; cbase = 256; at = true; }

  int r4 = (tid >> 5) * 4;        // compute rows
  int c4 = (tid & 31) * 4;        // compute cols
  int sr = tid >> 3;              // staging row 0..31
  int sk4 = (tid & 7) * 4;        // staging k offset
  int row = row0 + sr;
  int lx = (row >> 5) + dt;
  int b  = row & 31;
  bool valid = (unsigned)lx < 64u;
  const float* xrow = x + (lx * BB + b) * DIN;
  float mval = valid ? mask[lx * BB + b] : 0.0f;

  float acc[4][4] = {{0.f, 0.f, 0.f, 0.f}};
#pragma unroll 1
  for (int k0 = 0; k0 < 512; k0 += 32) {
    float4 xv = make_float4(0.f, 0.f, 0.f, 0.f);
    if (valid) xv = *(const float4*)(xrow + k0 + sk4);
    float4 wv[4];
#pragma unroll
    for (int rep = 0; rep < 4; ++rep) {
      int slot = rep * 256 + tid;
      int c = slot & 127;
      int kg4 = (slot >> 7) * 4;
      wv[rep] = *(const float4*)(wsrc + c * wstride + k0 + kg4);
    }
    __syncthreads();
    As[(sk4 + 0) * 36 + sr] = xv.x * mval;
    As[(sk4 + 1) * 36 + sr] = xv.y * mval;
    As[(sk4 + 2) * 36 + sr] = xv.z * mval;
    As[(sk4 + 3) * 36 + sr] = xv.w * mval;
#pragma unroll
    for (int rep = 0; rep < 4; ++rep) {
      int slot = rep * 256 + tid;
      int c = slot & 127;
      int kg4 = (slot >> 7) * 4;
      Ws[(kg4 + 0) * 132 + c] = wv[rep].x;
      Ws[(kg4 + 1) * 132 + c] = wv[rep].y;
      Ws[(kg4 + 2) * 132 + c] = wv[rep].z;
      Ws[(kg4 + 3) * 132 + c] = wv[rep].w;
    }
    __syncthreads();
#pragma unroll
    for (int kk = 0; kk < 32; ++kk) {
      float4 a = *(const float4*)&As[kk * 36 + r4];
      float4 w = *(const float4*)&Ws[kk * 132 + c4];
      float av[4] = {a.x, a.y, a.z, a.w};
      float wv2[4] = {w.x, w.y, w.z, w.w};
#pragma unroll
      for (int ri = 0; ri < 4; ++ri)
#pragma unroll
        for (int ci = 0; ci < 4; ++ci)
          acc[ri][ci] = fmaf(av[ri], wv2[ci], acc[ri][ci]);
    }
  }
#pragma unroll
  for (int ci = 0; ci < 4; ++ci) {
    int cout = cbase + c4 + ci;
    float* dst = yT + cout * 2048 + row0 + r4;
    if (at) {
      atomicAdd(dst + 0, acc[0][ci]);
      atomicAdd(dst + 1, acc[1][ci]);
      atomicAdd(dst + 2, acc[2][ci]);
      atomicAdd(dst + 3, acc[3][ci]);
    } else {
      *(float4*)dst = make_float4(acc[0][ci], acc[1][ci], acc[2][ci], acc[3][ci]);
    }
  }
}

// --------------------------------------------------------------- stats ------
__global__ __launch_bounds__(256) void stats_kernel(
    const float* __restrict__ yT,
    const float* __restrict__ g0, const float* __restrict__ be0,
    const float* __restrict__ g1, const float* __restrict__ be1,
    float* __restrict__ scale, float* __restrict__ shift)
{
  int c = blockIdx.x;
  int tid = threadIdx.x;
  const float* src = yT + c * 2048 + tid * 8;
  float4 v0 = *(const float4*)(src);
  float4 v1 = *(const float4*)(src + 4);
  float s  = v0.x + v0.y + v0.z + v0.w + v1.x + v1.y + v1.z + v1.w;
  float s2 = v0.x*v0.x + v0.y*v0.y + v0.z*v0.z + v0.w*v0.w
           + v1.x*v1.x + v1.y*v1.y + v1.z*v1.z + v1.w*v1.w;
#pragma unroll
  for (int off = 32; off > 0; off >>= 1) {
    s  += __shfl_down(s, off);
    s2 += __shfl_down(s2, off);
  }
  __shared__ float rs[4], rs2[4];
  int wid = tid >> 6;
  if ((tid & 63) == 0) { rs[wid] = s; rs2[wid] = s2; }
  __syncthreads();
  if (tid == 0) {
    float S  = rs[0] + rs[1] + rs[2] + rs[3];
    float S2 = rs2[0] + rs2[1] + rs2[2] + rs2[3];
    float mean = S * (1.f / 2048.f);
    float var  = S2 * (1.f / 2048.f) - mean * mean;
    float g  = (c < 256) ? g0[c] : g1[c - 256];
    float be = (c < 256) ? be0[c] : be1[c - 256];
    float sc = g / sqrtf(var + 1e-5f);
    scale[c] = sc;
    shift[c] = be - mean * sc;
  }
}

// ------------------------------------------------------------------ ab ------
// grid 256 = 64 row-tiles x 4 col-tiles(64). h computed on the fly from yT.
__global__ __launch_bounds__(256) void ab_kernel(
    const float* __restrict__ yT, const float* __restrict__ scale,
    const float* __restrict__ shift, const float* __restrict__ mask,
    const float* __restrict__ w0,
    float* __restrict__ a_arr, float* __restrict__ bb_arr)
{
  __shared__ float As[32 * 36];   // [c][r]
  __shared__ float Ws[32 * 68];   // [c][n]
  int bx = blockIdx.x;
  int rt = bx & 63, ct = bx >> 6;
  int row0 = rt * 32, n0 = ct * 64;
  int tid = threadIdx.x;
  int r4 = (tid >> 5) * 4;
  int n2 = (tid & 31) * 2;
  int scc = tid >> 3, srr4 = (tid & 7) * 4;
  int wnn8 = (tid & 7) * 8;
  const float* wbase = (n0 < 128) ? (w0 + n0) : (w0 + CCH * 128 + (n0 - 128));
  float4 mv = *(const float4*)(mask + row0 + srr4);

  float acc[4][2] = {{0.f, 0.f}};
#pragma unroll 1
  for (int c0 = 0; c0 < 384; c0 += 32) {
    int c = c0 + scc;
    float4 yv = *(const float4*)(yT + c * 2048 + row0 + srr4);
    float sc = scale[c], sh = shift[c];
    float4 wv0 = *(const float4*)(wbase + c * 128 + wnn8);
    float4 wv1 = *(const float4*)(wbase + c * 128 + wnn8 + 4);
    __syncthreads();
    float4 hv;
    hv.x = leaky(fmaf(yv.x, sc, sh)) * mv.x;
    hv.y = leaky(fmaf(yv.y, sc, sh)) * mv.y;
    hv.z = leaky(fmaf(yv.z, sc, sh)) * mv.z;
    hv.w = leaky(fmaf(yv.w, sc, sh)) * mv.w;
    *(float4*)&As[scc * 36 + srr4] = hv;
    *(float4*)&Ws[scc * 68 + wnn8] = wv0;
    *(float4*)&Ws[scc * 68 + wnn8 + 4] = wv1;
    __syncthreads();
#pragma unroll
    for (int cc = 0; cc < 32; ++cc) {
      float4 a = *(const float4*)&As[cc * 36 + r4];
      float2 w = *(const float2*)&Ws[cc * 68 + n2];
      acc[0][0] = fmaf(a.x, w.x, acc[0][0]); acc[0][1] = fmaf(a.x, w.y, acc[0][1]);
      acc[1][0] = fmaf(a.y, w.x, acc[1][0]); acc[1][1] = fmaf(a.y, w.y, acc[1][1]);
      acc[2][0] = fmaf(a.z, w.x, acc[2][0]); acc[2][1] = fmaf(a.z, w.y, acc[2][1]);
      acc[3][0] = fmaf(a.w, w.x, acc[3][0]); acc[3][1] = fmaf(a.w, w.y, acc[3][1]);
    }
  }
  float* dst; int nd;
  if (n0 < 128) { dst = a_arr; nd = n0; } else { dst = bb_arr; nd = n0 - 128; }
#pragma unroll
  for (int ri = 0; ri < 4; ++ri)
    *(float2*)&dst[(row0 + r4 + ri) * 128 + nd + n2] = make_float2(acc[ri][0], acc[ri][1]);
}

// ---------------------------------------------------------------- pair ------
// grid (64, 16): one block per (i, b-pair). 76KB LDS -> 2 blocks/CU.
__global__ __launch_bounds__(256, 2) void pair_kernel(
    const float* __restrict__ a_arr, const float* __restrict__ bb_arr,
    const float* __restrict__ b0,
    const float* __restrict__ w1, const float* __restrict__ b1,
    const float* __restrict__ w2, const float* __restrict__ b2,
    const float* __restrict__ w3, const float* __restrict__ b3,
    const float* __restrict__ w4, const float* __restrict__ b4,
    const float* __restrict__ w5, const float* __restrict__ b5,
    const float* __restrict__ mask, float* __restrict__ out)
{
  __shared__ float Al[128 * RS];  // activation tile, [c][r] (r = db*64 + j)
  __shared__ float Wl[16 * RS];   // 16-row weight chunk / pmean scratch
  int i = blockIdx.x, bp = blockIdx.y;
  int tid = threadIdx.x;
  int tx = tid & 15, ty = tid >> 4;
  int tx8 = tx * 8, ty8 = ty * 8;
  int wcc = tid >> 4, wk8 = (tid & 15) * 8;

  // p0 = leaky(a_i + bb_j + b0), stored transposed [c][r]
#pragma unroll 4
  for (int it = 0; it < 64; ++it) {
    int e = it * 256 + tid;
    int r = e >> 7, c = e & 127;
    int b = bp * 2 + (r >> 6);
    int j = r & 63;
    float v = a_arr[(i * BB + b) * 128 + c] + bb_arr[(j * BB + b) * 128 + c] + b0[c];
    Al[c * RS + r] = leaky(v);
  }
  __syncthreads();

  const float* Wp[3] = {w1, w2, w3};
  const float* Bp[3] = {b1, b2, b3};
  float acc[8][8];
#pragma unroll 1
  for (int layer = 0; layer < 3; ++layer) {
    const float* W  = Wp[layer];
    const float* Bb = Bp[layer];
    float4 bv0 = *(const float4*)(Bb + tx8);
    float4 bv1 = *(const float4*)(Bb + tx8 + 4);
    float bias[8] = {bv0.x, bv0.y, bv0.z, bv0.w, bv1.x, bv1.y, bv1.z, bv1.w};
#pragma unroll
    for (int u = 0; u < 8; ++u)
#pragma unroll
      for (int v = 0; v < 8; ++v) acc[u][v] = bias[v];

#pragma unroll 1
    for (int c0 = 0; c0 < 128; c0 += 16) {
      float4 wv0 = *(const float4*)(W + (c0 + wcc) * 128 + wk8);
      float4 wv1 = *(const float4*)(W + (c0 + wcc) * 128 + wk8 + 4);
      __syncthreads();
      *(float4*)&Wl[wcc * RS + wk8] = wv0;
      *(float4*)&Wl[wcc * RS + wk8 + 4] = wv1;
      __syncthreads();
#pragma unroll
      for (int cc = 0; cc < 16; ++cc) {
        const float* arow = &Al[(c0 + cc) * RS + ty8];
        float4 a0 = *(const float4*)(arow);
        float4 a1 = *(const float4*)(arow + 4);
        const float* wrow = &Wl[cc * RS + tx8];
        float4 f0 = *(const float4*)(wrow);
        float4 f1 = *(const float4*)(wrow + 4);
        float av[8] = {a0.x, a0.y, a0.z, a0.w, a1.x, a1.y, a1.z, a1.w};
        float wv[8] = {f0.x, f0.y, f0.z, f0.w, f1.x, f1.y, f1.z, f1.w};
#pragma unroll
        for (int u = 0; u < 8; ++u)
#pragma unroll
          for (int v = 0; v < 8; ++v)
            acc[u][v] = fmaf(av[u], wv[v], acc[u][v]);
      }
    }
#pragma unroll
    for (int u = 0; u < 8; ++u)
#pragma unroll
      for (int v = 0; v < 8; ++v) acc[u][v] = leaky(acc[u][v]);

    __syncthreads();  // all Al reads of this layer complete
    if (layer < 2) {
      // write back transposed: out col k -> next layer's c
#pragma unroll
      for (int v = 0; v < 8; ++v) {
        int k = tx8 + v;
        *(float4*)&Al[k * RS + ty8]     = make_float4(acc[0][v], acc[1][v], acc[2][v], acc[3][v]);
        *(float4*)&Al[k * RS + ty8 + 4] = make_float4(acc[4][v], acc[5][v], acc[6][v], acc[7][v]);
      }
      __syncthreads();
    }
  }

  // j-mean reduction: thread rows all share db = ty>>3
  float part[8];
#pragma unroll
  for (int v = 0; v < 8; ++v) {
    float s = acc[0][v];
#pragma unroll
    for (int u = 1; u < 8; ++u) s += acc[u][v];
    part[v] = s;
  }
  *(float4*)&Al[ty * RS + tx8]     = make_float4(part[0], part[1], part[2], part[3]);
  *(float4*)&Al[ty * RS + tx8 + 4] = make_float4(part[4], part[5], part[6], part[7]);
  __syncthreads();
  int db = tid >> 7;
  int k  = tid & 127;
  float s = 0.f;
#pragma unroll
  for (int t = 0; t < 8; ++t) s += Al[(db * 8 + t) * RS + k];
  int brow = i * BB + bp * 2 + db;
  float pm = s * (1.0f / 64.0f) * mask[brow];
  Wl[db * RS + k] = pm;
  __syncthreads();

  // t4 = leaky(pmean @ w4 + b4)
  float t4 = b4[k];
#pragma unroll 8
  for (int c = 0; c < 128; ++c)
    t4 = fmaf(Wl[db * RS + c], w4[c * 128 + k], t4);
  t4 = leaky(t4);
  Al[db * RS + k] = t4;   // partial reads all happened before previous barrier
  __syncthreads();

  // out = leaky(t4 @ w5 + b5) * mask ; 4 outputs/thread sharing w5 loads
  float o00 = b5[tid], o01 = b5[tid + 256];
  float o10 = o00, o11 = o01;
#pragma unroll 8
  for (int c = 0; c < 128; ++c) {
    float w5a = w5[c * 512 + tid];
    float w5b = w5[c * 512 + tid + 256];
    float al0 = Al[c];
    float al1 = Al[RS + c];
    o00 = fmaf(al0, w5a, o00); o01 = fmaf(al0, w5b, o01);
    o10 = fmaf(al1, w5a, o10); o11 = fmaf(al1, w5b, o11);
  }
  int rb = i * BB + bp * 2;
  float m0 = mask[rb], m1 = mask[rb + 1];
  float* ob = out + rb * 512;
  ob[tid]             = leaky(o00) * m0;
  ob[tid + 256]       = leaky(o01) * m0;
  ob[512 + tid]       = leaky(o10) * m1;
  ob[512 + tid + 256] = leaky(o11) * m1;
}

// -------------------------------------------------------------- launch ------
extern "C" void kernel_launch(void* const* d_in, const int* in_sizes, int n_in,
                              void* d_out, int out_size, void* d_ws, size_t ws_size,
                              hipStream_t stream) {
  const float* x    = (const float*)d_in[0];
  const float* mask = (const float*)d_in[1];
  const float* cw0  = (const float*)d_in[2];
  // d_in[3] conv_b0: cancels in BN
  const float* g0   = (const float*)d_in[4];
  const float* be0  = (const float*)d_in[5];
  const float* cw1  = (const float*)d_in[6];
  // d_in[7] conv_b1: cancels in BN
  const float* g1   = (const float*)d_in[8];
  const float* be1  = (const float*)d_in[9];
  const float* w0   = (const float*)d_in[10];
  const float* b0   = (const float*)d_in[11];
  const float* w1   = (const float*)d_in[12];
  const float* b1   = (const float*)d_in[13];
  const float* w2   = (const float*)d_in[14];
  const float* b2   = (const float*)d_in[15];
  const float* w3   = (const float*)d_in[16];
  const float* b3   = (const float*)d_in[17];
  const float* w4   = (const float*)d_in[18];
  const float* b4   = (const float*)d_in[19];
  const float* w5   = (const float*)d_in[20];
  const float* b5   = (const float*)d_in[21];

  float* ws     = (float*)d_ws;
  float* yT     = ws;                    // 384*2048
  float* scale  = ws + 786432;           // 384
  float* shift  = ws + 786816;           // 384
  float* a_arr  = ws + 787200;           // 2048*128
  float* bb_arr = ws + 1049344;          // 2048*128
  float* outp   = (float*)d_out;

  // zero win3 conv region (tap accumulation via atomics)
  hipMemsetAsync(yT + 256 * 2048, 0, 128 * 2048 * sizeof(float), stream);

  conv_kernel<<<320, 256, 0, stream>>>(x, mask, cw0, cw1, yT);
  stats_kernel<<<384, 256, 0, stream>>>(yT, g0, be0, g1, be1, scale, shift);
  ab_kernel<<<256, 256, 0, stream>>>(yT, scale, shift, mask, w0, a_arr, bb_arr);
  dim3 g5(64, 16);
  pair_kernel<<<g5, 256, 0, stream>>>(a_arr, bb_arr, b0, w1, b1, w2, b2, w3, b3,
                                      w4, b4, w5, b5, mask, outp);
}